// Round 4
// baseline (4517.428 us; speedup 1.0000x reference)
//
#include <hip/hip_runtime.h>

#define T_SEQ   1024
#define T_STEPS 1023
#define BATCH   128
#define DIM     256
#define HID     1024
#define VOUT    128
#define WGS     256
#define HSLOT   131072   // ushorts per t-slot: 8 slices x 16384
#define SLICE_E 16384    // h elems per slice per t (16 rows x 1024), frag-blocked [hk 32][lq 4][row 16][j 8]
#define XSLICE  4096     // x elems per slice per t (16 rows x 256),  frag-blocked [xk 8][lq][row][j]

typedef __attribute__((ext_vector_type(8))) short short8;
typedef __attribute__((ext_vector_type(4))) float floatx4;

// async global->LDS, 16B per lane (linear copy: LDS dest = uniform base + lane*16)
#define GLDS(gp, lp) __builtin_amdgcn_global_load_lds( \
    (const __attribute__((address_space(1))) unsigned int*)(gp), \
    (__attribute__((address_space(3))) unsigned int*)(lp), 16, 0, 0)

__device__ __forceinline__ unsigned short f2bf(float x) {
    union { float f; unsigned u; } v; v.f = x;
    unsigned r = v.u + 0x7FFFu + ((v.u >> 16) & 1u);   // RNE
    return (unsigned short)(r >> 16);
}
__device__ __forceinline__ float sigm(float x) { return 1.0f / (1.0f + __expf(-x)); }

__device__ __forceinline__ floatx4 shflx4(floatx4 v, int mask) {
    floatx4 r;
    #pragma unroll
    for (int i = 0; i < 4; ++i) r[i] = __shfl_xor(v[i], mask, 64);
    return r;
}
// select element 'row-within-quad' s (0..3) from a C-fragment
__device__ __forceinline__ float sel4(floatx4 v, int s) {
    const float v01 = (s & 1) ? v[1] : v[0];
    const float v23 = (s & 1) ? v[3] : v[2];
    return (s & 2) ? v23 : v01;
}

// ---------------- prep kernels ----------------

// h-weights bf16, wave-autonomous full-K order: [cg 32][w 8][hk 32][lane 64][j 8]
// B-frag col c = l&15 = gate*4 + p; output hcol = cg*32 + w*4 + p;
// W row R = gate*HID + hcol; K elem = hk*32 + (l>>4)*8 + j.
__global__ void pack_w(const float* __restrict__ Whh, unsigned short* __restrict__ Wph) {
    const size_t idx = (size_t)blockIdx.x * 256 + threadIdx.x;
    if (idx >= (size_t)32 * 8 * 32 * 64 * 8) return;   // 4,194,304
    const int j   = (int)(idx & 7);
    const int l   = (int)((idx >> 3) & 63);
    const int rest = (int)(idx >> 9);
    const int hk  = rest & 31;
    const int w   = (rest >> 5) & 7;
    const int cg  = rest >> 8;
    const int c = l & 15;
    const int gate = c >> 2, p = c & 3;
    const int R = gate * HID + cg * 32 + w * 4 + p;
    const int kcol = hk * 32 + (l >> 4) * 8 + j;
    Wph[idx] = f2bf(Whh[(size_t)R * HID + kcol]);
}

// x-weights bf16: [cg 32][w 8][xk 8][lane 64][j 8], same col mapping
__global__ void pack_xw(const float* __restrict__ Wih, unsigned short* __restrict__ Xw) {
    const size_t idx = (size_t)blockIdx.x * 256 + threadIdx.x;
    if (idx >= (size_t)32 * 8 * 8 * 64 * 8) return;    // 1,048,576
    const int j   = (int)(idx & 7);
    const int l   = (int)((idx >> 3) & 63);
    const int rest = (int)(idx >> 9);
    const int xk  = rest & 7;
    const int w   = (rest >> 3) & 7;
    const int cg  = rest >> 6;
    const int c = l & 15;
    const int gate = c >> 2, p = c & 3;
    const int R = gate * HID + cg * 32 + w * 4 + p;
    const int kcol = xk * 32 + (l >> 4) * 8 + j;
    Xw[idx] = f2bf(Wih[(size_t)R * DIM + kcol]);
}

// bias in natural (gate*H + hcol) order
__global__ void pack_bias(const float* __restrict__ bih, const float* __restrict__ bhh,
                          float* __restrict__ bc) {
    const int idx = blockIdx.x * 256 + threadIdx.x;
    if (idx < 4096) bc[idx] = bih[idx] + bhh[idx];
}

__global__ void pack_wout(const float* __restrict__ Wo, unsigned short* __restrict__ WoBf) {
    const int idx = blockIdx.x * 256 + threadIdx.x;
    if (idx < VOUT * HID) WoBf[idx] = f2bf(Wo[idx]);
}

// sequence [B, T, D] fp32 -> Xb [t][s8][xk 8][lq 4][row 16][j 8] bf16
__global__ void pack_x(const float* __restrict__ seq, unsigned short* __restrict__ Xb) {
    const size_t idx = (size_t)blockIdx.x * 256 + threadIdx.x;
    if (idx >= (size_t)T_STEPS * BATCH * DIM) return;
    const int j   = (int)(idx & 7);
    const int row = (int)((idx >> 3) & 15);
    const int lq  = (int)((idx >> 7) & 3);
    const int kk  = (int)((idx >> 9) & 7);
    const int s8  = (int)((idx >> 12) & 7);
    const int t   = (int)(idx >> 15);
    const int b = s8 * 16 + row;
    const int k = kk * 32 + lq * 8 + j;
    Xb[idx] = f2bf(seq[((size_t)b * T_SEQ + t) * DIM + k]);
}

__global__ void init_state(unsigned short* __restrict__ Hb, int* __restrict__ bar) {
    const int idx = blockIdx.x * 256 + threadIdx.x;
    if (idx < HSLOT) Hb[idx] = 0;          // t=0 slot zeros
    if (idx < 4096) bar[idx] = 0;          // per-wave flags (epoch 0 = h(0) ready)
}

// ---------------- persistent recurrent kernel ----------------
// 256 WGs x 512 threads, 1 WG/CU. Slice s8 = wg&7 (16 rows) owned by 32 WGs.
// WAVE-AUTONOMOUS: wave (cg,w) owns 16 gate-cols (4 hcols x 4 gates) x full K=1280
// -> no cross-wave reduction, no gl staging. h(t) staged to LDS once per WG
// (one sync/step); gates exchanged in-wave via shfl_xor butterfly; per-wave
// epoch flags (256/slice); 4 independent MFMA accumulation chains.
__global__ __launch_bounds__(512, 1) void lstm_persist(
    const unsigned short* __restrict__ Xb,
    unsigned short* __restrict__ Hblk,
    const unsigned short* __restrict__ Wph,
    const unsigned short* __restrict__ Xw,
    const float* __restrict__ bc,
    int* __restrict__ bar)
{
    __shared__ short8 xwl[4096];   // 64 KB x-weight frags [w 8][xk 8][lane 64]
    __shared__ short8 hl[2048];    // 32 KB h(t) slice, frag-blocked

    const int wg  = blockIdx.x;
    const int s8  = wg & 7;
    const int cg  = wg >> 3;
    const int tid = threadIdx.x;
    const int w   = tid >> 6;
    const int l   = tid & 63;
    const int c   = l & 15;        // MFMA col: gate*4 + p
    const int q   = l >> 4;        // row quad
    const int gate = c >> 2;
    const int p    = c & 3;

    // stage x-weights (64 KB) once
    {
        const unsigned short* xsrc = Xw + (size_t)cg * 32768;
        #pragma unroll
        for (int i = 0; i < 8; ++i)
            GLDS(xsrc + i * 4096 + tid * 8, (unsigned short*)xwl + i * 4096 + tid * 8);
    }

    // h-weight fragments -> registers/AGPRs (held all steps): 32 x short8
    const short8* wpw = (const short8*)Wph + (size_t)(cg * 8 + w) * 32 * 64 + l;
    short8 bh[32];
    #pragma unroll
    for (int i = 0; i < 32; ++i) bh[i] = wpw[i * 64];

    // own-column bias (covers this lane's gate column; butterfly carries it)
    const float bcol = bc[gate * HID + cg * 32 + w * 4 + p];
    float creg = 0.f;              // cell state for cell (row = q*4+gate, hcol p)

    __syncthreads();   // xwl ready

    const short8* xwv = xwl + (w * 8) * 64 + l;
    const short8* hv  = hl + l;
    const unsigned short* xa0 = Xb + (size_t)s8 * XSLICE + (size_t)l * 8;
    int* flagme = &bar[s8 * 256 + cg * 8 + w];
    const int* fb = bar + s8 * 256 + l * 4;

    const floatx4 z = {0.f, 0.f, 0.f, 0.f};
    floatx4 aA = z, aB = z, aC = z, aD = z;

    // x-partials for t=0 (2 chains)
    #pragma unroll
    for (int xk = 0; xk < 8; xk += 2) {
        short8 a0v = *(const short8*)(xa0 + xk * 512);
        short8 a1v = *(const short8*)(xa0 + (xk + 1) * 512);
        aA = __builtin_amdgcn_mfma_f32_16x16x32_bf16(a0v, xwv[xk * 64],       aA, 0, 0, 0);
        aB = __builtin_amdgcn_mfma_f32_16x16x32_bf16(a1v, xwv[(xk + 1) * 64], aB, 0, 0, 0);
    }

    long bud = 1L << 22;

    for (int t = 0; t < T_STEPS; ++t) {
        // ---- poll: all 256 producer waves of this slice at epoch >= t ----
        while (true) {
            const int f0 = __hip_atomic_load(fb + 0, __ATOMIC_RELAXED, __HIP_MEMORY_SCOPE_AGENT);
            const int f1 = __hip_atomic_load(fb + 1, __ATOMIC_RELAXED, __HIP_MEMORY_SCOPE_AGENT);
            const int f2 = __hip_atomic_load(fb + 2, __ATOMIC_RELAXED, __HIP_MEMORY_SCOPE_AGENT);
            const int f3 = __hip_atomic_load(fb + 3, __ATOMIC_RELAXED, __HIP_MEMORY_SCOPE_AGENT);
            const int mn = min(min(f0, f1), min(f2, f3));
            if (__all(mn >= t)) break;
            if (--bud < 0) break;
        }
        asm volatile("" ::: "memory");
        __builtin_amdgcn_sched_barrier(0);

        // ---- stage h(t) slice to LDS: 4 x 16B per thread, linear ----
        {
            const unsigned short* hs = Hblk + (size_t)t * HSLOT + (size_t)s8 * SLICE_E;
            #pragma unroll
            for (int i = 0; i < 4; ++i)
                GLDS(hs + i * 4096 + tid * 8, (unsigned short*)hl + i * 4096 + tid * 8);
        }
        __syncthreads();   // hl ready (drains GLDS); safe: flags ordered prior reads

        // ---- h GEMM: 32 frags over 4 independent chains ----
        #pragma unroll
        for (int f = 0; f < 32; f += 4) {
            short8 h0 = hv[(f + 0) * 64];
            short8 h1 = hv[(f + 1) * 64];
            short8 h2 = hv[(f + 2) * 64];
            short8 h3 = hv[(f + 3) * 64];
            aA = __builtin_amdgcn_mfma_f32_16x16x32_bf16(h0, bh[f + 0], aA, 0, 0, 0);
            aB = __builtin_amdgcn_mfma_f32_16x16x32_bf16(h1, bh[f + 1], aB, 0, 0, 0);
            aC = __builtin_amdgcn_mfma_f32_16x16x32_bf16(h2, bh[f + 2], aC, 0, 0, 0);
            aD = __builtin_amdgcn_mfma_f32_16x16x32_bf16(h3, bh[f + 3], aD, 0, 0, 0);
        }
        floatx4 acc = (aA + aB) + (aC + aD);
        #pragma unroll
        for (int r = 0; r < 4; ++r) acc[r] += bcol;

        // ---- in-wave gate butterfly (C layout: col=l&15, row=q*4+reg) ----
        const floatx4 t1 = shflx4(acc, 4);                  // gate bit0 partner
        floatx4 ev, od;
        #pragma unroll
        for (int r = 0; r < 4; ++r) {
            ev[r] = (gate & 1) ? t1[r] : acc[r];            // gate in {i,g}
            od[r] = (gate & 1) ? acc[r] : t1[r];            // gate in {f,o}
        }
        const floatx4 t2 = shflx4(ev, 8);
        const floatx4 t3 = shflx4(od, 8);
        floatx4 gI, gF, gG, gO;
        #pragma unroll
        for (int r = 0; r < 4; ++r) {
            gI[r] = (gate & 2) ? t2[r] : ev[r];
            gG[r] = (gate & 2) ? ev[r] : t2[r];
            gF[r] = (gate & 2) ? t3[r] : od[r];
            gO[r] = (gate & 2) ? od[r] : t3[r];
        }

        // ---- one cell per lane: row = q*4 + gate, hcol p ----
        const float iv = sigm(sel4(gI, gate));
        const float fv = sigm(sel4(gF, gate));
        const float gv = tanhf(sel4(gG, gate));
        const float ov = sigm(sel4(gO, gate));
        creg = fv * creg + iv * gv;
        const unsigned hu = (unsigned)f2bf(ov * tanhf(creg));
        const unsigned hup = (unsigned)__shfl_xor((int)hu, 1, 64);

        // ---- store h(t+1): 32 lanes, one dword each, write-through (IC) ----
        if ((c & 1) == 0) {
            const int row = q * 4 + gate;
            unsigned* hp = (unsigned*)(Hblk + (size_t)(t + 1) * HSLOT
                          + (size_t)s8 * SLICE_E + (size_t)cg * 512)
                          + ((w >> 1) * 64 + row * 4 + (w & 1) * 2 + (p >> 1));
            __hip_atomic_store(hp, hu | (hup << 16), __ATOMIC_RELAXED, __HIP_MEMORY_SCOPE_AGENT);
        }
        asm volatile("s_waitcnt vmcnt(0)" ::: "memory");    // data at coherence point

        aA = z; aB = z; aC = z; aD = z;
        if (t + 1 < T_STEPS) {
            if (l == 0)
                __hip_atomic_store(flagme, t + 1, __ATOMIC_RELAXED, __HIP_MEMORY_SCOPE_AGENT);

            // ---- x-partials for t+1 fill the flag round-trip window ----
            const unsigned short* xp = xa0 + (size_t)(t + 1) * (BATCH * DIM);
            #pragma unroll
            for (int xk = 0; xk < 8; xk += 2) {
                short8 a0v = *(const short8*)(xp + xk * 512);
                short8 a1v = *(const short8*)(xp + (xk + 1) * 512);
                aA = __builtin_amdgcn_mfma_f32_16x16x32_bf16(a0v, xwv[xk * 64],       aA, 0, 0, 0);
                aB = __builtin_amdgcn_mfma_f32_16x16x32_bf16(a1v, xwv[(xk + 1) * 64], aB, 0, 0, 0);
            }
        }
    }
}

// ---------------- deferred head: logits + log-softmax ----------------
__global__ __launch_bounds__(256, 2) void head_ls(
    const unsigned short* __restrict__ Hblk,
    const unsigned short* __restrict__ Wo,
    const float* __restrict__ bo,
    float* __restrict__ out)
{
    const int bg = blockIdx.x;    // slice 0..7
    const int t  = blockIdx.y;    // 0..1022
    const int tid = threadIdx.x;
    const int w  = tid >> 6;
    const int l  = tid & 63;
    const int lr = l & 15;
    const int lq = l >> 4;
    const int b0 = bg * 16;

    const short8* ap = (const short8*)(Hblk + (size_t)(t + 1) * HSLOT
                       + (size_t)bg * SLICE_E) + l;
    const unsigned short* bp0 = Wo + (size_t)(w * 32 + lr) * HID + lq * 8;
    const unsigned short* bp1 = Wo + (size_t)(w * 32 + 16 + lr) * HID + lq * 8;

    floatx4 a0 = {0.f, 0.f, 0.f, 0.f}, a1 = {0.f, 0.f, 0.f, 0.f};
    #pragma unroll 8
    for (int kk = 0; kk < 32; ++kk) {
        short8 a   = ap[kk * 64];
        short8 b0v = *(const short8*)(bp0 + kk * 32);
        short8 b1v = *(const short8*)(bp1 + kk * 32);
        a0 = __builtin_amdgcn_mfma_f32_16x16x32_bf16(a, b0v, a0, 0, 0, 0);
        a1 = __builtin_amdgcn_mfma_f32_16x16x32_bf16(a, b1v, a1, 0, 0, 0);
    }

    __shared__ float lg[16][132];
    #pragma unroll
    for (int r = 0; r < 4; ++r) {
        lg[lq * 4 + r][w * 32 + lr]      = a0[r] + bo[w * 32 + lr];
        lg[lq * 4 + r][w * 32 + 16 + lr] = a1[r] + bo[w * 32 + 16 + lr];
    }
    __syncthreads();

    const int row = tid >> 4;
    const int cc  = tid & 15;
    float vals[8];
    float m = -1e30f;
    #pragma unroll
    for (int jv = 0; jv < 8; ++jv) { vals[jv] = lg[row][cc + jv * 16]; m = fmaxf(m, vals[jv]); }
    #pragma unroll
    for (int d = 8; d >= 1; d >>= 1) m = fmaxf(m, __shfl_xor(m, d, 16));
    float ssum = 0.f;
    #pragma unroll
    for (int jv = 0; jv < 8; ++jv) ssum += __expf(vals[jv] - m);
    #pragma unroll
    for (int d = 8; d >= 1; d >>= 1) ssum += __shfl_xor(ssum, d, 16);
    const float lse = m + __logf(ssum);

    float* op = out + ((size_t)(b0 + row) * T_STEPS + t) * VOUT;
    #pragma unroll
    for (int jv = 0; jv < 8; ++jv) op[cc + jv * 16] = vals[jv] - lse;
}

// ---------------- launcher ----------------
extern "C" void kernel_launch(void* const* d_in, const int* in_sizes, int n_in,
                              void* d_out, int out_size, void* d_ws, size_t ws_size,
                              hipStream_t stream) {
    const float* seq  = (const float*)d_in[0];
    const float* Wih  = (const float*)d_in[1];
    const float* Whh  = (const float*)d_in[2];
    const float* bih  = (const float*)d_in[3];
    const float* bhh  = (const float*)d_in[4];
    const float* Wout = (const float*)d_in[5];
    const float* bout = (const float*)d_in[6];
    float* out = (float*)d_out;

    char* p = (char*)d_ws;
    unsigned short* Wph  = (unsigned short*)p; p += (size_t)32 * 8 * 32 * 64 * 8 * 2;       // 8 MB
    unsigned short* Xw   = (unsigned short*)p; p += (size_t)32 * 8 * 8 * 64 * 8 * 2;        // 2 MB
    unsigned short* WoBf = (unsigned short*)p; p += (size_t)VOUT * HID * 2;                 // 256 KB
    float*          bc   = (float*)p;          p += (size_t)4096 * 4;                       // 16 KB
    int*            bar  = (int*)p;            p += (size_t)4096 * 4;                       // 16 KB
    unsigned short* Xb   = (unsigned short*)p; p += (size_t)T_STEPS * BATCH * DIM * 2;      // 67 MB
    unsigned short* Hblk = (unsigned short*)p; p += (size_t)(T_STEPS + 1) * HSLOT * 2;      // 268 MB

    pack_w    <<<16384, 256, 0, stream>>>(Whh, Wph);
    pack_xw   <<<4096,  256, 0, stream>>>(Wih, Xw);
    pack_bias <<<16,    256, 0, stream>>>(bih, bhh, bc);
    pack_wout <<<512,   256, 0, stream>>>(Wout, WoBf);
    pack_x    <<<130944,256, 0, stream>>>(seq, Xb);
    init_state<<<512,   256, 0, stream>>>(Hblk, bar);

    lstm_persist<<<WGS, 512, 0, stream>>>(Xb, Hblk, Wph, Xw, bc, bar);

    head_ls<<<dim3(8, T_STEPS), 256, 0, stream>>>(Hblk, WoBf, bout, out);
}

// Round 5
// 4366.784 us; speedup vs baseline: 1.0345x; 1.0345x over previous
//
#include <hip/hip_runtime.h>

#define T_SEQ   1024
#define T_STEPS 1023
#define BATCH   128
#define DIM     256
#define HID     1024
#define VOUT    128
#define WGS     256
#define HSLOT   131072   // ushorts per t-slot: 8 slices x 16384
#define SLICE_E 16384    // h elems per slice per t (16 rows x 1024), frag-blocked [hk 32][lq 4][row 16][j 8]
#define XSLICE  4096     // x elems per slice per t (16 rows x 256),  frag-blocked [xk 8][lq][row][j]

typedef __attribute__((ext_vector_type(8))) short short8;
typedef __attribute__((ext_vector_type(4))) float floatx4;

// async global->LDS, 16B per lane (linear copy: LDS dest = uniform base + lane*16)
#define GLDS(gp, lp) __builtin_amdgcn_global_load_lds( \
    (const __attribute__((address_space(1))) unsigned int*)(gp), \
    (__attribute__((address_space(3))) unsigned int*)(lp), 16, 0, 0)

__device__ __forceinline__ unsigned short f2bf(float x) {
    union { float f; unsigned u; } v; v.f = x;
    unsigned r = v.u + 0x7FFFu + ((v.u >> 16) & 1u);   // RNE
    return (unsigned short)(r >> 16);
}
__device__ __forceinline__ float sigm(float x) { return 1.0f / (1.0f + __expf(-x)); }

// ---------------- prep kernels ----------------

// h-weights bf16, wave-fragment order: [cg 32][w 8][i2 32][lane 64][j 8]
// w = cw*4+kw, i2 = tile*8+hi. Element: gate col gc = cw*64+tile*16+(l&15),
// h-col = (kw*8+hi)*32 + (l>>4)*8 + j. W row R = (gc>>5)*H + cg*32 + (gc&31).
__global__ void pack_w(const float* __restrict__ Whh, unsigned short* __restrict__ Wph) {
    const size_t idx = (size_t)blockIdx.x * 256 + threadIdx.x;
    if (idx >= (size_t)32 * 8 * 32 * 64 * 8) return;   // 4,194,304
    const int j   = (int)(idx & 7);
    const int l   = (int)((idx >> 3) & 63);
    const int rest = (int)(idx >> 9);
    const int i2  = rest & 31;
    const int w   = (rest >> 5) & 7;
    const int cg  = rest >> 8;
    const int tile = i2 >> 3, hi = i2 & 7;
    const int cw = w >> 2, kw = w & 3;
    const int gc = cw * 64 + tile * 16 + (l & 15);
    const int R  = (gc >> 5) * HID + cg * 32 + (gc & 31);
    const int hcol = (kw * 8 + hi) * 32 + (l >> 4) * 8 + j;
    Wph[idx] = f2bf(Whh[(size_t)R * HID + hcol]);
}

// x-weights bf16: [cg 32][w 8][fi 8][lane 64][j 8], fi = tile*2+xi,
// x-col = (kw*2+xi)*32 + (l>>4)*8 + j
__global__ void pack_xw(const float* __restrict__ Wih, unsigned short* __restrict__ Xw) {
    const size_t idx = (size_t)blockIdx.x * 256 + threadIdx.x;
    if (idx >= (size_t)32 * 8 * 8 * 64 * 8) return;    // 1,048,576
    const int j   = (int)(idx & 7);
    const int l   = (int)((idx >> 3) & 63);
    const int rest = (int)(idx >> 9);
    const int fi  = rest & 7;
    const int w   = (rest >> 3) & 7;
    const int cg  = rest >> 6;
    const int tile = fi >> 1, xi = fi & 1;
    const int cw = w >> 2, kw = w & 3;
    const int gc = cw * 64 + tile * 16 + (l & 15);
    const int R  = (gc >> 5) * HID + cg * 32 + (gc & 31);
    const int xcol = (kw * 2 + xi) * 32 + (l >> 4) * 8 + j;
    Xw[idx] = f2bf(Wih[(size_t)R * DIM + xcol]);
}

// bias in natural (gate*H + hcol) order
__global__ void pack_bias(const float* __restrict__ bih, const float* __restrict__ bhh,
                          float* __restrict__ bc) {
    const int idx = blockIdx.x * 256 + threadIdx.x;
    if (idx < 4096) bc[idx] = bih[idx] + bhh[idx];
}

__global__ void pack_wout(const float* __restrict__ Wo, unsigned short* __restrict__ WoBf) {
    const int idx = blockIdx.x * 256 + threadIdx.x;
    if (idx < VOUT * HID) WoBf[idx] = f2bf(Wo[idx]);
}

// sequence [B, T, D] fp32 -> Xb [t][s8][xk 8][lq 4][row 16][j 8] bf16
__global__ void pack_x(const float* __restrict__ seq, unsigned short* __restrict__ Xb) {
    const size_t idx = (size_t)blockIdx.x * 256 + threadIdx.x;
    if (idx >= (size_t)T_STEPS * BATCH * DIM) return;
    const int j   = (int)(idx & 7);
    const int row = (int)((idx >> 3) & 15);
    const int lq  = (int)((idx >> 7) & 3);
    const int kk  = (int)((idx >> 9) & 7);
    const int s8  = (int)((idx >> 12) & 7);
    const int t   = (int)(idx >> 15);
    const int b = s8 * 16 + row;
    const int k = kk * 32 + lq * 8 + j;
    Xb[idx] = f2bf(seq[((size_t)b * T_SEQ + t) * DIM + k]);
}

__global__ void init_state(unsigned short* __restrict__ Hb, int* __restrict__ bar) {
    const int idx = blockIdx.x * 256 + threadIdx.x;
    if (idx < HSLOT) Hb[idx] = 0;          // t=0 slot zeros
    if (idx < 4096) bar[idx] = 0;          // flags (epoch 0 = h(0) ready) + regcnt
}

// ---------------- persistent recurrent kernel ----------------
// 256 WGs x 512 threads, 1 WG/CU (LDS 98 KB forces it). Slice = ACTUAL XCD id
// (s_getreg XCC_ID + atomic registration): each XCD hosts exactly 32 of the 256
// co-resident WGs, so every slice's h exchange is intra-XCD by construction.
// h therefore moves through the XCD's own L2 via PLAIN write-back stores
// (contiguous 1 KB/WG) and plain fresh-address loads; only the 32 per-WG epoch
// flags go through IC (agent scope). Wave (cw,kw): 64 gate cols x 8 h-frags,
// h-weights resident (AGPR), x-weights in LDS, x-GEMM fills the flag window.
__global__ __launch_bounds__(512, 1) void lstm_persist(
    const unsigned short* __restrict__ Xb,
    unsigned short* __restrict__ Hblk,
    const unsigned short* __restrict__ Wph,
    const unsigned short* __restrict__ Xw,
    const float* __restrict__ bc,
    int* __restrict__ bar)
{
    __shared__ short8 xwl[64 * 64];   // 64 KB  x-weight frags [w*8+fi][lane]
    __shared__ float  gl[4][16][132]; // 33 KB  per-kw gate partials (padded)
    __shared__ int sreg[2];

    const int tid = threadIdx.x;
    const int w   = tid >> 6;
    const int l   = tid & 63;
    const int lr  = l & 15;
    const int lq  = l >> 4;
    const int cw  = w >> 2;
    const int kw  = w & 3;
    const int cbase = cw * 64;
    const int lq4 = lq * 4;

    // ---- dynamic XCD registration: slice = my XCD, cg = my rank on it ----
    if (tid == 0) {
        int xcd;
        asm volatile("s_getreg_b32 %0, hwreg(HW_REG_XCC_ID)" : "=s"(xcd));
        xcd &= 7;
        const int rank = __hip_atomic_fetch_add(&bar[384 + xcd], 1,
                             __ATOMIC_RELAXED, __HIP_MEMORY_SCOPE_AGENT);
        sreg[0] = xcd;
        sreg[1] = rank & 31;
    }
    __syncthreads();
    const int s8 = sreg[0];
    const int cg = sreg[1];

    // stage x-weights (64 KB) once
    {
        const unsigned short* xsrc = Xw + (size_t)cg * 32768;
        #pragma unroll
        for (int i = 0; i < 8; ++i)
            GLDS(xsrc + i * 4096 + tid * 8, (unsigned short*)xwl + i * 4096 + tid * 8);
    }

    // h-weight fragments -> unified RF (resident all steps): 32 x short8
    const short8* wpw = (const short8*)Wph + (size_t)(cg * 8 + w) * 32 * 64 + l;
    short8 bh[32];
    #pragma unroll
    for (int i = 0; i < 32; ++i) bh[i] = wpw[i * 64];

    // epilogue constants: tid = elq*128 + er*8 + ej -> cell (row er, h-col hc)
    const int er  = (tid >> 3) & 15;
    const int ej  = tid & 7;
    const int elq = tid >> 7;
    const int hc  = elq * 8 + ej;
    const float bi  = bc[0 * HID + cg * 32 + hc];
    const float bf_ = bc[1 * HID + cg * 32 + hc];
    const float bg  = bc[2 * HID + cg * 32 + hc];
    const float bo_ = bc[3 * HID + cg * 32 + hc];
    float creg = 0.f;

    __syncthreads();   // xwl ready

    // wave-local pointers
    const short8* xwv = xwl + (w * 8) * 64 + l;
    const unsigned short* hb0 = Hblk + (size_t)s8 * SLICE_E + (size_t)(kw * 8) * 512 + (size_t)l * 8;
    const unsigned short* xa0 = Xb + (size_t)s8 * XSLICE + (size_t)(kw * 2) * 512 + (size_t)l * 8;
    const int* fpoll = bar + s8 * 32 + (l & 31);
    int* flagme = bar + s8 * 32 + cg;

    // x-partials for t=0
    floatx4 acx0 = {0.f,0.f,0.f,0.f}, acx1 = acx0, acx2 = acx0, acx3 = acx0;
    #pragma unroll
    for (int xi = 0; xi < 2; ++xi) {
        short8 a = *(const short8*)(xa0 + xi * 512);
        acx0 = __builtin_amdgcn_mfma_f32_16x16x32_bf16(a, xwv[(0*2+xi)*64], acx0, 0,0,0);
        acx1 = __builtin_amdgcn_mfma_f32_16x16x32_bf16(a, xwv[(1*2+xi)*64], acx1, 0,0,0);
        acx2 = __builtin_amdgcn_mfma_f32_16x16x32_bf16(a, xwv[(2*2+xi)*64], acx2, 0,0,0);
        acx3 = __builtin_amdgcn_mfma_f32_16x16x32_bf16(a, xwv[(3*2+xi)*64], acx3, 0,0,0);
    }

    long bud = 1L << 22;

    for (int t = 0; t < T_STEPS; ++t) {
        // ---- poll: h(t) published by all 32 producers of this slice ----
        // (wave-parallel: 32 lanes x 32 flags, IC-scope loads, no sleep)
        while (true) {
            const int f = __hip_atomic_load(fpoll, __ATOMIC_RELAXED,
                                            __HIP_MEMORY_SCOPE_AGENT);
            if (__all(f >= t)) break;
            if (--bud < 0) break;
        }
        asm volatile("" ::: "memory");
        __builtin_amdgcn_sched_barrier(0);

        // ---- h phase: 8 fresh-address plain loads (same-XCD L2 hit) + 32 MFMAs ----
        {
            const unsigned short* hp = hb0 + (size_t)t * HSLOT;
            short8 ha[8];
            #pragma unroll
            for (int i = 0; i < 8; ++i) ha[i] = *(const short8*)(hp + i * 512);
            #pragma unroll
            for (int i = 0; i < 8; ++i) {
                acx0 = __builtin_amdgcn_mfma_f32_16x16x32_bf16(ha[i], bh[ 0 + i], acx0, 0,0,0);
                acx1 = __builtin_amdgcn_mfma_f32_16x16x32_bf16(ha[i], bh[ 8 + i], acx1, 0,0,0);
                acx2 = __builtin_amdgcn_mfma_f32_16x16x32_bf16(ha[i], bh[16 + i], acx2, 0,0,0);
                acx3 = __builtin_amdgcn_mfma_f32_16x16x32_bf16(ha[i], bh[24 + i], acx3, 0,0,0);
            }
        }

        // ---- stage gate partials (C/D: col=lane&15, row=lq*4+r) ----
        #pragma unroll
        for (int r = 0; r < 4; ++r) {
            gl[kw][lq4 + r][cbase      + lr] = acx0[r];
            gl[kw][lq4 + r][cbase + 16 + lr] = acx1[r];
            gl[kw][lq4 + r][cbase + 32 + lr] = acx2[r];
            gl[kw][lq4 + r][cbase + 48 + lr] = acx3[r];
        }
        __syncthreads();

        // ---- fused cell update: one cell per thread ----
        float gi = bi, gf = bf_, gg = bg, go = bo_;
        #pragma unroll
        for (int q = 0; q < 4; ++q) {
            gi += gl[q][er][ 0 + hc];
            gf += gl[q][er][32 + hc];
            gg += gl[q][er][64 + hc];
            go += gl[q][er][96 + hc];
        }
        const float iv = sigm(gi), fv = sigm(gf), ov = sigm(go);
        const float gv = tanhf(gg);
        creg = fv * creg + iv * gv;
        const unsigned hu = f2bf(ov * tanhf(creg));
        const unsigned up = (unsigned)__shfl_down((int)hu, 1);

        // ---- h store: PLAIN write-back (contiguous 1 KB/WG -> XCD L2) ----
        if ((tid & 1) == 0) {
            unsigned* hp = (unsigned*)(Hblk + (size_t)(t + 1) * HSLOT
                          + (size_t)s8 * SLICE_E + (size_t)cg * 512 + tid);
            *hp = hu | (up << 16);
        }
        asm volatile("s_waitcnt vmcnt(0)" ::: "memory");  // data ack'd at L2
        __syncthreads();                                  // all waves' stores done

        if (t + 1 < T_STEPS) {
            // publish h(t+1) (single IC store per WG)
            if (tid == 0)
                __hip_atomic_store(flagme, t + 1,
                                   __ATOMIC_RELAXED, __HIP_MEMORY_SCOPE_AGENT);

            // ---- x-partials for t+1 fill the publish->detect window ----
            const unsigned short* xp = xa0 + (size_t)(t + 1) * (BATCH * DIM);
            const floatx4 z = {0.f, 0.f, 0.f, 0.f};
            acx0 = z; acx1 = z; acx2 = z; acx3 = z;
            #pragma unroll
            for (int xi = 0; xi < 2; ++xi) {
                short8 a = *(const short8*)(xp + xi * 512);
                acx0 = __builtin_amdgcn_mfma_f32_16x16x32_bf16(a, xwv[(0*2+xi)*64], acx0, 0,0,0);
                acx1 = __builtin_amdgcn_mfma_f32_16x16x32_bf16(a, xwv[(1*2+xi)*64], acx1, 0,0,0);
                acx2 = __builtin_amdgcn_mfma_f32_16x16x32_bf16(a, xwv[(2*2+xi)*64], acx2, 0,0,0);
                acx3 = __builtin_amdgcn_mfma_f32_16x16x32_bf16(a, xwv[(3*2+xi)*64], acx3, 0,0,0);
            }
        }
    }
}

// ---------------- deferred head: logits + log-softmax ----------------
__global__ __launch_bounds__(256, 2) void head_ls(
    const unsigned short* __restrict__ Hblk,
    const unsigned short* __restrict__ Wo,
    const float* __restrict__ bo,
    float* __restrict__ out)
{
    const int bg = blockIdx.x;    // slice 0..7
    const int t  = blockIdx.y;    // 0..1022
    const int tid = threadIdx.x;
    const int w  = tid >> 6;
    const int l  = tid & 63;
    const int lr = l & 15;
    const int lq = l >> 4;
    const int b0 = bg * 16;

    const short8* ap = (const short8*)(Hblk + (size_t)(t + 1) * HSLOT
                       + (size_t)bg * SLICE_E) + l;
    const unsigned short* bp0 = Wo + (size_t)(w * 32 + lr) * HID + lq * 8;
    const unsigned short* bp1 = Wo + (size_t)(w * 32 + 16 + lr) * HID + lq * 8;

    floatx4 a0 = {0.f, 0.f, 0.f, 0.f}, a1 = {0.f, 0.f, 0.f, 0.f};
    #pragma unroll 8
    for (int kk = 0; kk < 32; ++kk) {
        short8 a   = ap[kk * 64];
        short8 b0v = *(const short8*)(bp0 + kk * 32);
        short8 b1v = *(const short8*)(bp1 + kk * 32);
        a0 = __builtin_amdgcn_mfma_f32_16x16x32_bf16(a, b0v, a0, 0, 0, 0);
        a1 = __builtin_amdgcn_mfma_f32_16x16x32_bf16(a, b1v, a1, 0, 0, 0);
    }

    __shared__ float lg[16][132];
    #pragma unroll
    for (int r = 0; r < 4; ++r) {
        lg[lq * 4 + r][w * 32 + lr]      = a0[r] + bo[w * 32 + lr];
        lg[lq * 4 + r][w * 32 + 16 + lr] = a1[r] + bo[w * 32 + 16 + lr];
    }
    __syncthreads();

    const int row = tid >> 4;
    const int c   = tid & 15;
    float vals[8];
    float m = -1e30f;
    #pragma unroll
    for (int jv = 0; jv < 8; ++jv) { vals[jv] = lg[row][c + jv * 16]; m = fmaxf(m, vals[jv]); }
    #pragma unroll
    for (int d = 8; d >= 1; d >>= 1) m = fmaxf(m, __shfl_xor(m, d, 16));
    float ssum = 0.f;
    #pragma unroll
    for (int jv = 0; jv < 8; ++jv) ssum += __expf(vals[jv] - m);
    #pragma unroll
    for (int d = 8; d >= 1; d >>= 1) ssum += __shfl_xor(ssum, d, 16);
    const float lse = m + __logf(ssum);

    float* op = out + ((size_t)(b0 + row) * T_STEPS + t) * VOUT;
    #pragma unroll
    for (int jv = 0; jv < 8; ++jv) op[c + jv * 16] = vals[jv] - lse;
}

// ---------------- launcher ----------------
extern "C" void kernel_launch(void* const* d_in, const int* in_sizes, int n_in,
                              void* d_out, int out_size, void* d_ws, size_t ws_size,
                              hipStream_t stream) {
    const float* seq  = (const float*)d_in[0];
    const float* Wih  = (const float*)d_in[1];
    const float* Whh  = (const float*)d_in[2];
    const float* bih  = (const float*)d_in[3];
    const float* bhh  = (const float*)d_in[4];
    const float* Wout = (const float*)d_in[5];
    const float* bout = (const float*)d_in[6];
    float* out = (float*)d_out;

    char* p = (char*)d_ws;
    unsigned short* Wph  = (unsigned short*)p; p += (size_t)32 * 8 * 32 * 64 * 8 * 2;       // 8 MB
    unsigned short* Xw   = (unsigned short*)p; p += (size_t)32 * 8 * 8 * 64 * 8 * 2;        // 2 MB
    unsigned short* WoBf = (unsigned short*)p; p += (size_t)VOUT * HID * 2;                 // 256 KB
    float*          bc   = (float*)p;          p += (size_t)4096 * 4;                       // 16 KB
    int*            bar  = (int*)p;            p += (size_t)4096 * 4;                       // 16 KB
    unsigned short* Xb   = (unsigned short*)p; p += (size_t)T_STEPS * BATCH * DIM * 2;      // 67 MB
    unsigned short* Hblk = (unsigned short*)p; p += (size_t)(T_STEPS + 1) * HSLOT * 2;      // 268 MB

    pack_w    <<<16384, 256, 0, stream>>>(Whh, Wph);
    pack_xw   <<<4096,  256, 0, stream>>>(Wih, Xw);
    pack_bias <<<16,    256, 0, stream>>>(bih, bhh, bc);
    pack_wout <<<512,   256, 0, stream>>>(Wout, WoBf);
    pack_x    <<<130944,256, 0, stream>>>(seq, Xb);
    init_state<<<512,   256, 0, stream>>>(Hblk, bar);

    lstm_persist<<<WGS, 512, 0, stream>>>(Xb, Hblk, Wph, Xw, bc, bar);

    head_ls<<<dim3(8, T_STEPS), 256, 0, stream>>>(Hblk, WoBf, bout, out);
}